// Round 3
// baseline (368.458 us; speedup 1.0000x reference)
//
#include <hip/hip_runtime.h>

#define DIM 1024
#define BATCH 4
#define SEQ 4096
#define NH 16
#define HD 64
#define KP 256

typedef float f32x4 __attribute__((ext_vector_type(4)));
typedef _Float16 half8 __attribute__((ext_vector_type(8)));

__device__ __forceinline__ void gll16(const void* g, void* l) {
  __builtin_amdgcn_global_load_lds(
      (const __attribute__((address_space(1))) void*)g,
      (__attribute__((address_space(3))) void*)l, 16, 0, 0);
}

// ---- fp32 -> fp16 elementwise convert, 8 elems/thread ----
__global__ void k_cvt(const float* __restrict__ s, _Float16* __restrict__ d) {
  int i = (blockIdx.x * 256 + threadIdx.x) * 8;
  f32x4 a = *(const f32x4*)(s + i);
  f32x4 b = *(const f32x4*)(s + i + 4);
  half8 h;
  h[0] = a[0]; h[1] = a[1]; h[2] = a[2]; h[3] = a[3];
  h[4] = b[0]; h[5] = b[1]; h[6] = b[2]; h[7] = b[3];
  *(half8*)(d + i) = h;
}

// Wq and Wo converts merged: grid 1024 blocks
__global__ void k_cvtw(const float* __restrict__ Wq, const float* __restrict__ Wo,
                       _Float16* __restrict__ Wq_h, _Float16* __restrict__ Wo_h) {
  int bb = blockIdx.x;
  const float* s = (bb < 512) ? Wq : Wo;
  _Float16* d = (bb < 512) ? Wq_h : Wo_h;
  int i = ((bb & 511) * 256 + threadIdx.x) * 8;
  f32x4 a = *(const f32x4*)(s + i);
  f32x4 b = *(const f32x4*)(s + i + 4);
  half8 h;
  h[0] = a[0]; h[1] = a[1]; h[2] = a[2]; h[3] = a[3];
  h[4] = b[0]; h[5] = b[1]; h[6] = b[2]; h[7] = b[3];
  *(half8*)(d + i) = h;
}

// misc small work merged: grid 88 blocks
//  0..15 : zero xsum (4096 floats)
// 16..23 : E fp32->fp16 (16384 elems, 8/thread)
// 24..87 : Ftp[d][col'] = F[k][d], col' = (k%16)*16 + k/16 (k-permuted transpose)
__global__ void k_misc(const float* __restrict__ E, const float* __restrict__ F,
                       _Float16* __restrict__ E_h, _Float16* __restrict__ Ft,
                       float* __restrict__ xsum) {
  int bb = blockIdx.x;
  if (bb < 16) {
    xsum[bb * 256 + threadIdx.x] = 0.f;
  } else if (bb < 24) {
    int i = ((bb - 16) * 256 + threadIdx.x) * 8;
    f32x4 a = *(const f32x4*)(E + i);
    f32x4 b = *(const f32x4*)(E + i + 4);
    half8 h;
    h[0] = a[0]; h[1] = a[1]; h[2] = a[2]; h[3] = a[3];
    h[4] = b[0]; h[5] = b[1]; h[6] = b[2]; h[7] = b[3];
    *(half8*)(E_h + i) = h;
  } else {
    int i = (bb - 24) * 256 + threadIdx.x;  // 16384
    int k = i >> 6, d = i & 63;
    Ft[d * KP + (k & 15) * 16 + (k >> 4)] = (_Float16)F[i];
  }
}

// xsum[b,c] = sum_n x[b,n,c]; reads fp16 x_h (half the traffic); grid (4,B,32)
__global__ void k_xsum(const _Float16* __restrict__ xh, float* __restrict__ xs) {
  int c = blockIdx.x * 256 + threadIdx.x;
  int b = blockIdx.y;
  int n0 = blockIdx.z * 128;
  const _Float16* p = xh + (size_t)(b * SEQ + n0) * DIM + c;
  float s = 0.f;
  #pragma unroll 8
  for (int i = 0; i < 128; i++) s += (float)p[i * DIM];
  atomicAdd(&xs[b * DIM + c], s);
}

// Sk[b,c] = xsum[b,:]@Wk[c,:], Sv likewise. One wave per output dot.
__global__ void k_sksv(const float* __restrict__ xs, const float* __restrict__ Wk,
                       const float* __restrict__ Wv, float* __restrict__ Sk,
                       float* __restrict__ Sv) {
  int idx = blockIdx.x * 4 + (threadIdx.x >> 6);
  int lane = threadIdx.x & 63;
  int kv = idx >> 12;
  int rem = idx & 4095;
  int b = rem >> 10, c = rem & 1023;
  const float* W = (kv ? Wv : Wk) + c * DIM;
  const float* xp = xs + b * DIM;
  float a = 0.f;
  #pragma unroll
  for (int i = 0; i < 16; i++) a += xp[lane + i * 64] * W[lane + i * 64];
  for (int off = 32; off; off >>= 1) a += __shfl_down(a, off);
  if (lane == 0) (kv ? Sv : Sk)[rem] = a;
}

// ---- fp16 MFMA GEMM, conflict-free k-group-major LDS: C = A @ Bw^T ----
// LDS layout per staging wave: [kg 0..3][row 0..31][8 halfs] (kg = k-chunk of 8).
// Staging lane L loads (row=L&31, kg=L>>5) -> frag-read bank = (mm*4)%32:
// 8 consecutive lanes hit 8 distinct bank-quads -> conflict-free; per-lane
// k-order preserved (row-swizzles would break MFMA contraction, this doesn't).
// MODE 0: out fp16 = acc * sb[b*DIM+col] * 0.125 * log2e  (Q proj)
// MODE 1: out fp32 = acc + sb[col]                        (out proj + bias)
template <int MODE>
__global__ __launch_bounds__(256) void k_gemm(const _Float16* __restrict__ A,
                                              const _Float16* __restrict__ Bw,
                                              void* __restrict__ Cout,
                                              const float* __restrict__ sb) {
  __shared__ _Float16 As[128 * 32];
  __shared__ _Float16 Bs[128 * 32];
  const int tid = threadIdx.x;
  const int w = tid >> 6, lane = tid & 63;
  const int m0 = blockIdx.x * 128, n0 = blockIdx.y * 128;
  const int q4 = lane >> 4, mm = lane & 15;
  const int wm = w & 1, wn = w >> 1;
  f32x4 acc[4][4] = {};
  // staging: lane L -> global row (base + (L&31)), k-chunk (L>>5)*8
  const _Float16* Ag = A + (m0 + w * 32 + (lane & 31)) * DIM + (lane >> 5) * 8;
  const _Float16* Bg = Bw + (n0 + w * 32 + (lane & 31)) * DIM + (lane >> 5) * 8;
  _Float16* AsW = As + w * 1024;
  _Float16* BsW = Bs + w * 1024;
  for (int k0 = 0; k0 < DIM; k0 += 32) {
    gll16(Ag + k0, AsW);            // kg 0,1
    gll16(Ag + k0 + 16, AsW + 512); // kg 2,3
    gll16(Bg + k0, BsW);
    gll16(Bg + k0 + 16, BsW + 512);
    __syncthreads();
    half8 av[4], bv[4];
    #pragma unroll
    for (int t = 0; t < 4; t++) {
      // row R = wm*64 + t*16 + mm lives in staging-wave (wm*2 + (t>>1)),
      // local row (t&1)*16+mm, k-chunk q4
      av[t] = *(const half8*)(As + (wm * 2 + (t >> 1)) * 1024 + q4 * 256 +
                              ((t & 1) * 16 + mm) * 8);
      bv[t] = *(const half8*)(Bs + (wn * 2 + (t >> 1)) * 1024 + q4 * 256 +
                              ((t & 1) * 16 + mm) * 8);
    }
    #pragma unroll
    for (int mt = 0; mt < 4; mt++)
      #pragma unroll
      for (int nt = 0; nt < 4; nt++)
        acc[mt][nt] = __builtin_amdgcn_mfma_f32_16x16x32_f16(av[mt], bv[nt], acc[mt][nt], 0, 0, 0);
    __syncthreads();
  }
  const int bIdx = m0 >> 12;
  #pragma unroll
  for (int nt = 0; nt < 4; nt++) {
    int colg = n0 + wn * 64 + nt * 16 + mm;
    float s = (MODE == 0) ? sb[bIdx * DIM + colg] * (0.125f * 1.44269504088896f)
                          : sb[colg];
    #pragma unroll
    for (int mt = 0; mt < 4; mt++) {
      int rowg = m0 + wm * 64 + mt * 16 + q4 * 4;
      #pragma unroll
      for (int r = 0; r < 4; r++) {
        float v = acc[mt][nt][r];
        if (MODE == 0)
          ((_Float16*)Cout)[(rowg + r) * DIM + colg] = (_Float16)(v * s);
        else
          ((float*)Cout)[(rowg + r) * DIM + colg] = v + s;
      }
    }
  }
}

// ---- fused attention v3: grid (16,64) = 1024 blocks (4/CU), 4 tiles/wave ----
// E/F frags preloaded per wave (reused 4x); ~2 waves/SIMD resident gives
// cross-wave hiding of the softmax chain (v2 ran 1 wave/SIMD -> serial).
__global__ __launch_bounds__(256) void k_attn(const _Float16* __restrict__ Q,
                                              const _Float16* __restrict__ E,
                                              const _Float16* __restrict__ Ftp,
                                              const float* __restrict__ Sv,
                                              _Float16* __restrict__ O) {
  __shared__ _Float16 Ps[4][16][264];  // per-wave 16x256 P tile, +8 pad
  const int tid = threadIdx.x;
  const int w = tid >> 6, lane = tid & 63;
  const int q4 = lane >> 4, mm = lane & 15;
  const int bh = blockIdx.y;
  const int b = bh >> 4, h = bh & 15;
  const int row_base = blockIdx.x * 256 + w * 64;  // 4 tiles of 16 rows

  half8 ef[16][2];
  #pragma unroll
  for (int t = 0; t < 16; t++)
    #pragma unroll
    for (int kk = 0; kk < 2; kk++)
      ef[t][kk] = *(const half8*)(E + (t * 16 + mm) * HD + kk * 32 + q4 * 8);
  half8 ff[4][8];  // k-permuted Ftp B-frags
  #pragma unroll
  for (int nt = 0; nt < 4; nt++)
    #pragma unroll
    for (int kk = 0; kk < 8; kk++)
      ff[nt][kk] = *(const half8*)(Ftp + (nt * 16 + mm) * KP + kk * 32 + q4 * 8);
  float sv[4];
  #pragma unroll
  for (int nt = 0; nt < 4; nt++) sv[nt] = Sv[b * DIM + h * HD + nt * 16 + mm];

  const _Float16* Qbase = Q + ((size_t)(b * SEQ + row_base + mm)) * DIM + h * HD + q4 * 8;
  half8 qa0 = *(const half8*)(Qbase);
  half8 qa1 = *(const half8*)(Qbase + 32);

  for (int tile = 0; tile < 4; tile++) {
    f32x4 acc[16] = {};
    #pragma unroll
    for (int t = 0; t < 16; t++)
      acc[t] = __builtin_amdgcn_mfma_f32_16x16x32_f16(qa0, ef[t][0], acc[t], 0, 0, 0);
    #pragma unroll
    for (int t = 0; t < 16; t++)
      acc[t] = __builtin_amdgcn_mfma_f32_16x16x32_f16(qa1, ef[t][1], acc[t], 0, 0, 0);
    half8 qn0, qn1;
    if (tile < 3) {
      const _Float16* Qn = Qbase + (size_t)(tile + 1) * 16 * DIM;
      qn0 = *(const half8*)(Qn);
      qn1 = *(const half8*)(Qn + 32);
    }
    // softmax over 256 cols (base-2; log2e folded into Q upstream)
    float mx[4] = {-1e30f, -1e30f, -1e30f, -1e30f};
    #pragma unroll
    for (int t = 0; t < 16; t++)
      #pragma unroll
      for (int r = 0; r < 4; r++) mx[r] = fmaxf(mx[r], acc[t][r]);
    #pragma unroll
    for (int r = 0; r < 4; r++)
      for (int msk = 1; msk < 16; msk <<= 1) mx[r] = fmaxf(mx[r], __shfl_xor(mx[r], msk));
    float sm[4] = {0.f, 0.f, 0.f, 0.f};
    #pragma unroll
    for (int t = 0; t < 16; t++)
      #pragma unroll
      for (int r = 0; r < 4; r++) {
        float p = __builtin_amdgcn_exp2f(acc[t][r] - mx[r]);
        acc[t][r] = p;
        sm[r] += p;
      }
    #pragma unroll
    for (int r = 0; r < 4; r++) {
      for (int msk = 1; msk < 16; msk <<= 1) sm[r] += __shfl_xor(sm[r], msk);
      sm[r] = 1.f / sm[r];
    }
    // P -> LDS in permuted-col layout: (row, k=t*16+mm) -> col' = mm*16 + t
    #pragma unroll
    for (int r = 0; r < 4; r++) {
      half8 h0, h1;
      #pragma unroll
      for (int t = 0; t < 8; t++) h0[t] = (_Float16)(acc[t][r] * sm[r]);
      #pragma unroll
      for (int t = 0; t < 8; t++) h1[t] = (_Float16)(acc[t + 8][r] * sm[r]);
      *(half8*)&Ps[w][q4 * 4 + r][mm * 16] = h0;
      *(half8*)&Ps[w][q4 * 4 + r][mm * 16 + 8] = h1;
    }
    // phase 2: out = P @ F (both in permuted k-order), then * Sv
    f32x4 acc2[4] = {};
    #pragma unroll
    for (int kk = 0; kk < 8; kk++) {
      half8 pa = *(const half8*)&Ps[w][mm][kk * 32 + q4 * 8];
      #pragma unroll
      for (int nt = 0; nt < 4; nt++)
        acc2[nt] = __builtin_amdgcn_mfma_f32_16x16x32_f16(pa, ff[nt][kk], acc2[nt], 0, 0, 0);
    }
    const int rw0 = row_base + tile * 16;
    #pragma unroll
    for (int nt = 0; nt < 4; nt++)
      #pragma unroll
      for (int r = 0; r < 4; r++)
        O[(size_t)(b * SEQ + rw0 + q4 * 4 + r) * DIM + h * HD + nt * 16 + mm] =
            (_Float16)(acc2[nt][r] * sv[nt]);
    qa0 = qn0;
    qa1 = qn1;
  }
}

extern "C" void kernel_launch(void* const* d_in, const int* in_sizes, int n_in,
                              void* d_out, int out_size, void* d_ws, size_t ws_size,
                              hipStream_t stream) {
  (void)in_sizes; (void)n_in; (void)out_size; (void)ws_size;
  const float* x  = (const float*)d_in[0];
  const float* Wq = (const float*)d_in[1];
  const float* Wk = (const float*)d_in[2];
  const float* Wv = (const float*)d_in[3];
  const float* E  = (const float*)d_in[4];
  const float* F  = (const float*)d_in[5];
  const float* Wo = (const float*)d_in[6];
  const float* bo = (const float*)d_in[7];
  char* ws = (char*)d_ws;
  // workspace layout (68.1 MB); O_h aliases x_h (x_h dead after Q GEMM)
  _Float16* x_h  = (_Float16*)(ws);
  _Float16* O_h  = (_Float16*)(ws);
  _Float16* Q_h  = (_Float16*)(ws + 33554432);
  _Float16* Wq_h = (_Float16*)(ws + 67108864);
  _Float16* Wo_h = (_Float16*)(ws + 69206016);
  _Float16* E_h  = (_Float16*)(ws + 71303168);
  _Float16* Ft_h = (_Float16*)(ws + 71335936);
  float* xsum    = (float*)(ws + 71368704);
  float* Sk      = (float*)(ws + 71385088);
  float* Sv      = (float*)(ws + 71401472);
  float* out     = (float*)d_out;

  k_cvt<<<8192, 256, 0, stream>>>(x, x_h);
  k_misc<<<88, 256, 0, stream>>>(E, F, E_h, Ft_h, xsum);
  k_cvtw<<<1024, 256, 0, stream>>>(Wq, Wo, Wq_h, Wo_h);
  k_xsum<<<dim3(4, BATCH, 32), 256, 0, stream>>>(x_h, xsum);
  k_sksv<<<2048, 256, 0, stream>>>(xsum, Wk, Wv, Sk, Sv);
  k_gemm<0><<<dim3(128, 8), 256, 0, stream>>>(x_h, Wq_h, (void*)Q_h, Sk);
  k_attn<<<dim3(16, 64), 256, 0, stream>>>(Q_h, E_h, Ft_h, Sv, O_h);
  k_gemm<1><<<dim3(128, 8), 256, 0, stream>>>(O_h, Wo_h, (void*)out, bo);
}

// Round 4
// 335.664 us; speedup vs baseline: 1.0977x; 1.0977x over previous
//
#include <hip/hip_runtime.h>

#define DIM 1024
#define BATCH 4
#define SEQ 4096
#define NH 16
#define HD 64
#define KP 256

typedef float f32x4 __attribute__((ext_vector_type(4)));
typedef _Float16 half8 __attribute__((ext_vector_type(8)));

__device__ __forceinline__ void gll16(const void* g, void* l) {
  __builtin_amdgcn_global_load_lds(
      (const __attribute__((address_space(1))) void*)g,
      (__attribute__((address_space(3))) void*)l, 16, 0, 0);
}

// ---- fp32 -> fp16 elementwise convert, 8 elems/thread ----
__global__ void k_cvt(const float* __restrict__ s, _Float16* __restrict__ d) {
  int i = (blockIdx.x * 256 + threadIdx.x) * 8;
  f32x4 a = *(const f32x4*)(s + i);
  f32x4 b = *(const f32x4*)(s + i + 4);
  half8 h;
  h[0] = a[0]; h[1] = a[1]; h[2] = a[2]; h[3] = a[3];
  h[4] = b[0]; h[5] = b[1]; h[6] = b[2]; h[7] = b[3];
  *(half8*)(d + i) = h;
}

// Wq and Wo converts merged: grid 1024 blocks
__global__ void k_cvtw(const float* __restrict__ Wq, const float* __restrict__ Wo,
                       _Float16* __restrict__ Wq_h, _Float16* __restrict__ Wo_h) {
  int bb = blockIdx.x;
  const float* s = (bb < 512) ? Wq : Wo;
  _Float16* d = (bb < 512) ? Wq_h : Wo_h;
  int i = ((bb & 511) * 256 + threadIdx.x) * 8;
  f32x4 a = *(const f32x4*)(s + i);
  f32x4 b = *(const f32x4*)(s + i + 4);
  half8 h;
  h[0] = a[0]; h[1] = a[1]; h[2] = a[2]; h[3] = a[3];
  h[4] = b[0]; h[5] = b[1]; h[6] = b[2]; h[7] = b[3];
  *(half8*)(d + i) = h;
}

// misc small work merged: grid 88 blocks
//  0..15 : zero xsum; 16..23 : E cvt; 24..87 : Ftp (k-permuted transpose of F)
__global__ void k_misc(const float* __restrict__ E, const float* __restrict__ F,
                       _Float16* __restrict__ E_h, _Float16* __restrict__ Ft,
                       float* __restrict__ xsum) {
  int bb = blockIdx.x;
  if (bb < 16) {
    xsum[bb * 256 + threadIdx.x] = 0.f;
  } else if (bb < 24) {
    int i = ((bb - 16) * 256 + threadIdx.x) * 8;
    f32x4 a = *(const f32x4*)(E + i);
    f32x4 b = *(const f32x4*)(E + i + 4);
    half8 h;
    h[0] = a[0]; h[1] = a[1]; h[2] = a[2]; h[3] = a[3];
    h[4] = b[0]; h[5] = b[1]; h[6] = b[2]; h[7] = b[3];
    *(half8*)(E_h + i) = h;
  } else {
    int i = (bb - 24) * 256 + threadIdx.x;  // 16384
    int k = i >> 6, d = i & 63;
    Ft[d * KP + (k & 15) * 16 + (k >> 4)] = (_Float16)F[i];
  }
}

// xsum[b,c] = sum_n x[b,n,c]; reads fp16 x_h; grid (4,B,32)
__global__ void k_xsum(const _Float16* __restrict__ xh, float* __restrict__ xs) {
  int c = blockIdx.x * 256 + threadIdx.x;
  int b = blockIdx.y;
  int n0 = blockIdx.z * 128;
  const _Float16* p = xh + (size_t)(b * SEQ + n0) * DIM + c;
  float s = 0.f;
  #pragma unroll 8
  for (int i = 0; i < 128; i++) s += (float)p[i * DIM];
  atomicAdd(&xs[b * DIM + c], s);
}

// Sk[b,c] = xsum[b,:]@Wk[c,:], Sv likewise. One wave per output dot.
__global__ void k_sksv(const float* __restrict__ xs, const float* __restrict__ Wk,
                       const float* __restrict__ Wv, float* __restrict__ Sk,
                       float* __restrict__ Sv) {
  int idx = blockIdx.x * 4 + (threadIdx.x >> 6);
  int lane = threadIdx.x & 63;
  int kv = idx >> 12;
  int rem = idx & 4095;
  int b = rem >> 10, c = rem & 1023;
  const float* W = (kv ? Wv : Wk) + c * DIM;
  const float* xp = xs + b * DIM;
  float a = 0.f;
  #pragma unroll
  for (int i = 0; i < 16; i++) a += xp[lane + i * 64] * W[lane + i * 64];
  for (int off = 32; off; off >>= 1) a += __shfl_down(a, off);
  if (lane == 0) (kv ? Sv : Sk)[rem] = a;
}

// ---- fp16 MFMA GEMM (round-2 staging: 4 lanes/row, 64B/row segments) ----
// Epilogue repacks C through the dead As/Bs LDS so stores are full 128B lines.
// Note: the 4-way-looking SQ_LDS_BANK_CONFLICT on frag reads is throughput-
// neutral (64 lanes spread evenly over 8 bank-quads = the 8-cycle b128 floor);
// round-3's "fix" wrecked staging coalescing (16B/lane scatter) and cost 19us.
// MODE 0: out fp16 = acc * sb[b*DIM+col] * 0.125 * log2e  (Q proj)
// MODE 1: out fp32 = acc + sb[col]                        (out proj + bias)
template <int MODE>
__global__ __launch_bounds__(256) void k_gemm(const _Float16* __restrict__ A,
                                              const _Float16* __restrict__ Bw,
                                              void* __restrict__ Cout,
                                              const float* __restrict__ sb) {
  __shared__ _Float16 sh[2][128 * 32];  // As,Bs; reused as 16KB repack buffer
  _Float16* As = sh[0];
  _Float16* Bs = sh[1];
  const int tid = threadIdx.x;
  const int w = tid >> 6, lane = tid & 63;
  const int m0 = blockIdx.x * 128, n0 = blockIdx.y * 128;
  const int q4 = lane >> 4, mm = lane & 15;
  const int wm = w & 1, wn = w >> 1;
  f32x4 acc[4][4] = {};
  const _Float16* Ag = A + (m0 + w * 32 + (lane >> 2)) * DIM + (lane & 3) * 8;
  const _Float16* Bg = Bw + (n0 + w * 32 + (lane >> 2)) * DIM + (lane & 3) * 8;
  _Float16* AsW = As + w * 1024;
  _Float16* BsW = Bs + w * 1024;
  for (int k0 = 0; k0 < DIM; k0 += 32) {
    gll16(Ag + k0, AsW);
    gll16(Ag + k0 + 16 * DIM, AsW + 512);
    gll16(Bg + k0, BsW);
    gll16(Bg + k0 + 16 * DIM, BsW + 512);
    __syncthreads();
    half8 av[4], bv[4];
    const _Float16* Ap = As + (wm * 64 + mm) * 32 + q4 * 8;
    const _Float16* Bp = Bs + (wn * 64 + mm) * 32 + q4 * 8;
    #pragma unroll
    for (int t = 0; t < 4; t++) {
      av[t] = *(const half8*)(Ap + t * 512);
      bv[t] = *(const half8*)(Bp + t * 512);
    }
    #pragma unroll
    for (int mt = 0; mt < 4; mt++)
      #pragma unroll
      for (int nt = 0; nt < 4; nt++)
        acc[mt][nt] = __builtin_amdgcn_mfma_f32_16x16x32_f16(av[mt], bv[nt], acc[mt][nt], 0, 0, 0);
    __syncthreads();
  }
  if (MODE == 0) {
    // 2 passes x 64 rows x 128 fp16 cols (16 KB)
    _Float16* Lh = (_Float16*)sh;
    #pragma unroll
    for (int p = 0; p < 2; p++) {
      if (wm == p) {
        #pragma unroll
        for (int nt = 0; nt < 4; nt++) {
          int cl = wn * 64 + nt * 16 + mm;
          float s = sb[(m0 >> 12) * DIM + n0 + cl] * (0.125f * 1.44269504088896f);
          #pragma unroll
          for (int mt = 0; mt < 4; mt++) {
            int rl = mt * 16 + q4 * 4;
            #pragma unroll
            for (int r = 0; r < 4; r++)
              Lh[(rl + r) * 128 + cl] = (_Float16)(acc[mt][nt][r] * s);
          }
        }
      }
      __syncthreads();
      int row_l = tid >> 2, c0 = (tid & 3) * 32;  // 4 threads/row, 64B each
      _Float16* dst = (_Float16*)Cout + (size_t)(m0 + p * 64 + row_l) * DIM + n0 + c0;
      #pragma unroll
      for (int i = 0; i < 4; i++)
        *(half8*)(dst + i * 8) = *(half8*)(Lh + row_l * 128 + c0 + i * 8);
      __syncthreads();
    }
  } else {
    // 4 passes x 32 rows x 128 fp32 cols (16 KB)
    float* Lf = (float*)sh;
    #pragma unroll
    for (int p = 0; p < 4; p++) {
      if (wm == (p >> 1)) {
        #pragma unroll
        for (int nt = 0; nt < 4; nt++) {
          int cl = wn * 64 + nt * 16 + mm;
          float s = sb[n0 + cl];
          #pragma unroll
          for (int mti = 0; mti < 2; mti++) {
            int mt = (p & 1) * 2 + mti;
            int rl = mt * 16 + q4 * 4 - (p & 1) * 32;
            #pragma unroll
            for (int r = 0; r < 4; r++)
              Lf[(rl + r) * 128 + cl] = acc[mt][nt][r] + s;
          }
        }
      }
      __syncthreads();
      int row_l = tid >> 3, c0 = (tid & 7) * 16;  // 8 threads/row, 64B each
      float* dst = (float*)Cout + (size_t)(m0 + p * 32 + row_l) * DIM + n0 + c0;
      #pragma unroll
      for (int i = 0; i < 4; i++)
        *(f32x4*)(dst + i * 4) = *(f32x4*)(Lf + row_l * 128 + c0 + i * 4);
      __syncthreads();
    }
  }
}

// ---- fused attention v3: grid (16,64) = 1024 blocks, 4 tiles/wave ----
__global__ __launch_bounds__(256) void k_attn(const _Float16* __restrict__ Q,
                                              const _Float16* __restrict__ E,
                                              const _Float16* __restrict__ Ftp,
                                              const float* __restrict__ Sv,
                                              _Float16* __restrict__ O) {
  __shared__ _Float16 Ps[4][16][264];
  const int tid = threadIdx.x;
  const int w = tid >> 6, lane = tid & 63;
  const int q4 = lane >> 4, mm = lane & 15;
  const int bh = blockIdx.y;
  const int b = bh >> 4, h = bh & 15;
  const int row_base = blockIdx.x * 256 + w * 64;

  half8 ef[16][2];
  #pragma unroll
  for (int t = 0; t < 16; t++)
    #pragma unroll
    for (int kk = 0; kk < 2; kk++)
      ef[t][kk] = *(const half8*)(E + (t * 16 + mm) * HD + kk * 32 + q4 * 8);
  half8 ff[4][8];
  #pragma unroll
  for (int nt = 0; nt < 4; nt++)
    #pragma unroll
    for (int kk = 0; kk < 8; kk++)
      ff[nt][kk] = *(const half8*)(Ftp + (nt * 16 + mm) * KP + kk * 32 + q4 * 8);
  float sv[4];
  #pragma unroll
  for (int nt = 0; nt < 4; nt++) sv[nt] = Sv[b * DIM + h * HD + nt * 16 + mm];

  const _Float16* Qbase = Q + ((size_t)(b * SEQ + row_base + mm)) * DIM + h * HD + q4 * 8;
  half8 qa0 = *(const half8*)(Qbase);
  half8 qa1 = *(const half8*)(Qbase + 32);

  for (int tile = 0; tile < 4; tile++) {
    f32x4 acc[16] = {};
    #pragma unroll
    for (int t = 0; t < 16; t++)
      acc[t] = __builtin_amdgcn_mfma_f32_16x16x32_f16(qa0, ef[t][0], acc[t], 0, 0, 0);
    #pragma unroll
    for (int t = 0; t < 16; t++)
      acc[t] = __builtin_amdgcn_mfma_f32_16x16x32_f16(qa1, ef[t][1], acc[t], 0, 0, 0);
    half8 qn0, qn1;
    if (tile < 3) {
      const _Float16* Qn = Qbase + (size_t)(tile + 1) * 16 * DIM;
      qn0 = *(const half8*)(Qn);
      qn1 = *(const half8*)(Qn + 32);
    }
    float mx[4] = {-1e30f, -1e30f, -1e30f, -1e30f};
    #pragma unroll
    for (int t = 0; t < 16; t++)
      #pragma unroll
      for (int r = 0; r < 4; r++) mx[r] = fmaxf(mx[r], acc[t][r]);
    #pragma unroll
    for (int r = 0; r < 4; r++)
      for (int msk = 1; msk < 16; msk <<= 1) mx[r] = fmaxf(mx[r], __shfl_xor(mx[r], msk));
    float sm[4] = {0.f, 0.f, 0.f, 0.f};
    #pragma unroll
    for (int t = 0; t < 16; t++)
      #pragma unroll
      for (int r = 0; r < 4; r++) {
        float p = __builtin_amdgcn_exp2f(acc[t][r] - mx[r]);
        acc[t][r] = p;
        sm[r] += p;
      }
    #pragma unroll
    for (int r = 0; r < 4; r++) {
      for (int msk = 1; msk < 16; msk <<= 1) sm[r] += __shfl_xor(sm[r], msk);
      sm[r] = 1.f / sm[r];
    }
    #pragma unroll
    for (int r = 0; r < 4; r++) {
      half8 h0, h1;
      #pragma unroll
      for (int t = 0; t < 8; t++) h0[t] = (_Float16)(acc[t][r] * sm[r]);
      #pragma unroll
      for (int t = 0; t < 8; t++) h1[t] = (_Float16)(acc[t + 8][r] * sm[r]);
      *(half8*)&Ps[w][q4 * 4 + r][mm * 16] = h0;
      *(half8*)&Ps[w][q4 * 4 + r][mm * 16 + 8] = h1;
    }
    f32x4 acc2[4] = {};
    #pragma unroll
    for (int kk = 0; kk < 8; kk++) {
      half8 pa = *(const half8*)&Ps[w][mm][kk * 32 + q4 * 8];
      #pragma unroll
      for (int nt = 0; nt < 4; nt++)
        acc2[nt] = __builtin_amdgcn_mfma_f32_16x16x32_f16(pa, ff[nt][kk], acc2[nt], 0, 0, 0);
    }
    const int rw0 = row_base + tile * 16;
    #pragma unroll
    for (int nt = 0; nt < 4; nt++)
      #pragma unroll
      for (int r = 0; r < 4; r++)
        O[(size_t)(b * SEQ + rw0 + q4 * 4 + r) * DIM + h * HD + nt * 16 + mm] =
            (_Float16)(acc2[nt][r] * sv[nt]);
    qa0 = qn0;
    qa1 = qn1;
  }
}

extern "C" void kernel_launch(void* const* d_in, const int* in_sizes, int n_in,
                              void* d_out, int out_size, void* d_ws, size_t ws_size,
                              hipStream_t stream) {
  (void)in_sizes; (void)n_in; (void)out_size; (void)ws_size;
  const float* x  = (const float*)d_in[0];
  const float* Wq = (const float*)d_in[1];
  const float* Wk = (const float*)d_in[2];
  const float* Wv = (const float*)d_in[3];
  const float* E  = (const float*)d_in[4];
  const float* F  = (const float*)d_in[5];
  const float* Wo = (const float*)d_in[6];
  const float* bo = (const float*)d_in[7];
  char* ws = (char*)d_ws;
  _Float16* x_h  = (_Float16*)(ws);
  _Float16* O_h  = (_Float16*)(ws);          // aliases x_h (dead after Q GEMM)
  _Float16* Q_h  = (_Float16*)(ws + 33554432);
  _Float16* Wq_h = (_Float16*)(ws + 67108864);
  _Float16* Wo_h = (_Float16*)(ws + 69206016);
  _Float16* E_h  = (_Float16*)(ws + 71303168);
  _Float16* Ft_h = (_Float16*)(ws + 71335936);
  float* xsum    = (float*)(ws + 71368704);
  float* Sk      = (float*)(ws + 71385088);
  float* Sv      = (float*)(ws + 71401472);
  float* out     = (float*)d_out;

  k_cvt<<<8192, 256, 0, stream>>>(x, x_h);
  k_misc<<<88, 256, 0, stream>>>(E, F, E_h, Ft_h, xsum);
  k_cvtw<<<1024, 256, 0, stream>>>(Wq, Wo, Wq_h, Wo_h);
  k_xsum<<<dim3(4, BATCH, 32), 256, 0, stream>>>(x_h, xsum);
  k_sksv<<<2048, 256, 0, stream>>>(xsum, Wk, Wv, Sk, Sv);
  k_gemm<0><<<dim3(128, 8), 256, 0, stream>>>(x_h, Wq_h, (void*)Q_h, Sk);
  k_attn<<<dim3(16, 64), 256, 0, stream>>>(Q_h, E_h, Ft_h, Sv, O_h);
  k_gemm<1><<<dim3(128, 8), 256, 0, stream>>>(O_h, Wo_h, (void*)out, bo);
}

// Round 5
// 315.227 us; speedup vs baseline: 1.1689x; 1.0648x over previous
//
#include <hip/hip_runtime.h>

#define DIM 1024
#define BATCH 4
#define SEQ 4096
#define NH 16
#define HD 64
#define KP 256

typedef float f32x4 __attribute__((ext_vector_type(4)));
typedef _Float16 half8 __attribute__((ext_vector_type(8)));

__device__ __forceinline__ void gll16(const void* g, void* l) {
  __builtin_amdgcn_global_load_lds(
      (const __attribute__((address_space(1))) void*)g,
      (__attribute__((address_space(3))) void*)l, 16, 0, 0);
}

// DPP row_ror:n within 16-lane rows (VALU-latency cross-lane; our reduction
// groups are exactly the 16-lane DPP rows). ctrl = 0x120|n.
#define DPPF(v, ctrl)                                                        \
  __builtin_bit_cast(float, __builtin_amdgcn_mov_dpp(                        \
                                __builtin_bit_cast(int, v), ctrl, 0xF, 0xF, true))

// ---- fp32 -> fp16 elementwise convert, 8 elems/thread ----
__global__ void k_cvt(const float* __restrict__ s, _Float16* __restrict__ d) {
  int i = (blockIdx.x * 256 + threadIdx.x) * 8;
  f32x4 a = *(const f32x4*)(s + i);
  f32x4 b = *(const f32x4*)(s + i + 4);
  half8 h;
  h[0] = a[0]; h[1] = a[1]; h[2] = a[2]; h[3] = a[3];
  h[4] = b[0]; h[5] = b[1]; h[6] = b[2]; h[7] = b[3];
  *(half8*)(d + i) = h;
}

// Wq and Wo converts merged: grid 1024 blocks
__global__ void k_cvtw(const float* __restrict__ Wq, const float* __restrict__ Wo,
                       _Float16* __restrict__ Wq_h, _Float16* __restrict__ Wo_h) {
  int bb = blockIdx.x;
  const float* s = (bb < 512) ? Wq : Wo;
  _Float16* d = (bb < 512) ? Wq_h : Wo_h;
  int i = ((bb & 511) * 256 + threadIdx.x) * 8;
  f32x4 a = *(const f32x4*)(s + i);
  f32x4 b = *(const f32x4*)(s + i + 4);
  half8 h;
  h[0] = a[0]; h[1] = a[1]; h[2] = a[2]; h[3] = a[3];
  h[4] = b[0]; h[5] = b[1]; h[6] = b[2]; h[7] = b[3];
  *(half8*)(d + i) = h;
}

// misc small work merged: grid 88 blocks
__global__ void k_misc(const float* __restrict__ E, const float* __restrict__ F,
                       _Float16* __restrict__ E_h, _Float16* __restrict__ Ft,
                       float* __restrict__ xsum) {
  int bb = blockIdx.x;
  if (bb < 16) {
    xsum[bb * 256 + threadIdx.x] = 0.f;
  } else if (bb < 24) {
    int i = ((bb - 16) * 256 + threadIdx.x) * 8;
    f32x4 a = *(const f32x4*)(E + i);
    f32x4 b = *(const f32x4*)(E + i + 4);
    half8 h;
    h[0] = a[0]; h[1] = a[1]; h[2] = a[2]; h[3] = a[3];
    h[4] = b[0]; h[5] = b[1]; h[6] = b[2]; h[7] = b[3];
    *(half8*)(E_h + i) = h;
  } else {
    int i = (bb - 24) * 256 + threadIdx.x;  // 16384
    int k = i >> 6, d = i & 63;
    Ft[d * KP + (k & 15) * 16 + (k >> 4)] = (_Float16)F[i];
  }
}

// xsum[b,c] = sum_n x[b,n,c]; reads fp16 x_h; grid (4,B,32)
__global__ void k_xsum(const _Float16* __restrict__ xh, float* __restrict__ xs) {
  int c = blockIdx.x * 256 + threadIdx.x;
  int b = blockIdx.y;
  int n0 = blockIdx.z * 128;
  const _Float16* p = xh + (size_t)(b * SEQ + n0) * DIM + c;
  float s = 0.f;
  #pragma unroll 8
  for (int i = 0; i < 128; i++) s += (float)p[i * DIM];
  atomicAdd(&xs[b * DIM + c], s);
}

// Sk[b,c] = xsum[b,:]@Wk[c,:], Sv likewise. One wave per output dot.
__global__ void k_sksv(const float* __restrict__ xs, const float* __restrict__ Wk,
                       const float* __restrict__ Wv, float* __restrict__ Sk,
                       float* __restrict__ Sv) {
  int idx = blockIdx.x * 4 + (threadIdx.x >> 6);
  int lane = threadIdx.x & 63;
  int kv = idx >> 12;
  int rem = idx & 4095;
  int b = rem >> 10, c = rem & 1023;
  const float* W = (kv ? Wv : Wk) + c * DIM;
  const float* xp = xs + b * DIM;
  float a = 0.f;
  #pragma unroll
  for (int i = 0; i < 16; i++) a += xp[lane + i * 64] * W[lane + i * 64];
  for (int off = 32; off; off >>= 1) a += __shfl_down(a, off);
  if (lane == 0) (kv ? Sv : Sk)[rem] = a;
}

// ---- fp16 MFMA GEMM (round-2 staging) + LDS-repacked full-line epilogue ----
// MODE 0: out fp16 = acc * sb[b*DIM+col] * 0.125 * log2e  (Q proj)
// MODE 1: out fp32 = acc + sb[col]                        (out proj + bias)
template <int MODE>
__global__ __launch_bounds__(256) void k_gemm(const _Float16* __restrict__ A,
                                              const _Float16* __restrict__ Bw,
                                              void* __restrict__ Cout,
                                              const float* __restrict__ sb) {
  __shared__ _Float16 sh[2][128 * 32];
  _Float16* As = sh[0];
  _Float16* Bs = sh[1];
  const int tid = threadIdx.x;
  const int w = tid >> 6, lane = tid & 63;
  const int m0 = blockIdx.x * 128, n0 = blockIdx.y * 128;
  const int q4 = lane >> 4, mm = lane & 15;
  const int wm = w & 1, wn = w >> 1;
  f32x4 acc[4][4] = {};
  const _Float16* Ag = A + (m0 + w * 32 + (lane >> 2)) * DIM + (lane & 3) * 8;
  const _Float16* Bg = Bw + (n0 + w * 32 + (lane >> 2)) * DIM + (lane & 3) * 8;
  _Float16* AsW = As + w * 1024;
  _Float16* BsW = Bs + w * 1024;
  for (int k0 = 0; k0 < DIM; k0 += 32) {
    gll16(Ag + k0, AsW);
    gll16(Ag + k0 + 16 * DIM, AsW + 512);
    gll16(Bg + k0, BsW);
    gll16(Bg + k0 + 16 * DIM, BsW + 512);
    __syncthreads();
    half8 av[4], bv[4];
    const _Float16* Ap = As + (wm * 64 + mm) * 32 + q4 * 8;
    const _Float16* Bp = Bs + (wn * 64 + mm) * 32 + q4 * 8;
    #pragma unroll
    for (int t = 0; t < 4; t++) {
      av[t] = *(const half8*)(Ap + t * 512);
      bv[t] = *(const half8*)(Bp + t * 512);
    }
    #pragma unroll
    for (int mt = 0; mt < 4; mt++)
      #pragma unroll
      for (int nt = 0; nt < 4; nt++)
        acc[mt][nt] = __builtin_amdgcn_mfma_f32_16x16x32_f16(av[mt], bv[nt], acc[mt][nt], 0, 0, 0);
    __syncthreads();
  }
  if (MODE == 0) {
    _Float16* Lh = (_Float16*)sh;
    #pragma unroll
    for (int p = 0; p < 2; p++) {
      if (wm == p) {
        #pragma unroll
        for (int nt = 0; nt < 4; nt++) {
          int cl = wn * 64 + nt * 16 + mm;
          float s = sb[(m0 >> 12) * DIM + n0 + cl] * (0.125f * 1.44269504088896f);
          #pragma unroll
          for (int mt = 0; mt < 4; mt++) {
            int rl = mt * 16 + q4 * 4;
            #pragma unroll
            for (int r = 0; r < 4; r++)
              Lh[(rl + r) * 128 + cl] = (_Float16)(acc[mt][nt][r] * s);
          }
        }
      }
      __syncthreads();
      int row_l = tid >> 2, c0 = (tid & 3) * 32;
      _Float16* dst = (_Float16*)Cout + (size_t)(m0 + p * 64 + row_l) * DIM + n0 + c0;
      #pragma unroll
      for (int i = 0; i < 4; i++)
        *(half8*)(dst + i * 8) = *(half8*)(Lh + row_l * 128 + c0 + i * 8);
      __syncthreads();
    }
  } else {
    float* Lf = (float*)sh;
    #pragma unroll
    for (int p = 0; p < 4; p++) {
      if (wm == (p >> 1)) {
        #pragma unroll
        for (int nt = 0; nt < 4; nt++) {
          int cl = wn * 64 + nt * 16 + mm;
          float s = sb[n0 + cl];
          #pragma unroll
          for (int mti = 0; mti < 2; mti++) {
            int mt = (p & 1) * 2 + mti;
            int rl = mt * 16 + q4 * 4 - (p & 1) * 32;
            #pragma unroll
            for (int r = 0; r < 4; r++)
              Lf[(rl + r) * 128 + cl] = acc[mt][nt][r] + s;
          }
        }
      }
      __syncthreads();
      int row_l = tid >> 3, c0 = (tid & 7) * 16;
      float* dst = (float*)Cout + (size_t)(m0 + p * 32 + row_l) * DIM + n0 + c0;
      #pragma unroll
      for (int i = 0; i < 4; i++)
        *(f32x4*)(dst + i * 4) = *(f32x4*)(Lf + row_l * 128 + c0 + i * 4);
      __syncthreads();
    }
  }
}

// ---- fused attention v4: grid (8,64)=512 blocks, 8 tiles/wave ----
// DPP row_ror butterflies for the 16-lane softmax reductions (VALU latency,
// not ds_bpermute's ~120cyc); P normalization deferred to the epilogue
// (out linear in P; phase-1/phase-2 C-layout row mapping identical).
__global__ __launch_bounds__(256) void k_attn(const _Float16* __restrict__ Q,
                                              const _Float16* __restrict__ E,
                                              const _Float16* __restrict__ Ftp,
                                              const float* __restrict__ Sv,
                                              _Float16* __restrict__ O) {
  __shared__ _Float16 Ps[4][16][264];
  const int tid = threadIdx.x;
  const int w = tid >> 6, lane = tid & 63;
  const int q4 = lane >> 4, mm = lane & 15;
  const int bh = blockIdx.y;
  const int b = bh >> 4, h = bh & 15;
  const int row_base = blockIdx.x * 512 + w * 128;  // 8 tiles of 16 rows

  half8 ef[16][2];
  #pragma unroll
  for (int t = 0; t < 16; t++)
    #pragma unroll
    for (int kk = 0; kk < 2; kk++)
      ef[t][kk] = *(const half8*)(E + (t * 16 + mm) * HD + kk * 32 + q4 * 8);
  half8 ff[4][8];
  #pragma unroll
  for (int nt = 0; nt < 4; nt++)
    #pragma unroll
    for (int kk = 0; kk < 8; kk++)
      ff[nt][kk] = *(const half8*)(Ftp + (nt * 16 + mm) * KP + kk * 32 + q4 * 8);
  float sv[4];
  #pragma unroll
  for (int nt = 0; nt < 4; nt++) sv[nt] = Sv[b * DIM + h * HD + nt * 16 + mm];

  const _Float16* Qbase = Q + ((size_t)(b * SEQ + row_base + mm)) * DIM + h * HD + q4 * 8;
  half8 qa0 = *(const half8*)(Qbase);
  half8 qa1 = *(const half8*)(Qbase + 32);

  for (int tile = 0; tile < 8; tile++) {
    f32x4 acc[16] = {};
    #pragma unroll
    for (int t = 0; t < 16; t++)
      acc[t] = __builtin_amdgcn_mfma_f32_16x16x32_f16(qa0, ef[t][0], acc[t], 0, 0, 0);
    #pragma unroll
    for (int t = 0; t < 16; t++)
      acc[t] = __builtin_amdgcn_mfma_f32_16x16x32_f16(qa1, ef[t][1], acc[t], 0, 0, 0);
    half8 qn0, qn1;
    if (tile < 7) {
      const _Float16* Qn = Qbase + (size_t)(tile + 1) * 16 * DIM;
      qn0 = *(const half8*)(Qn);
      qn1 = *(const half8*)(Qn + 32);
    }
    // rowwise max over 256 cols (base-2 logits; log2e folded upstream)
    float mx[4] = {-1e30f, -1e30f, -1e30f, -1e30f};
    #pragma unroll
    for (int t = 0; t < 16; t++)
      #pragma unroll
      for (int r = 0; r < 4; r++) mx[r] = fmaxf(mx[r], acc[t][r]);
    #pragma unroll
    for (int r = 0; r < 4; r++) {
      float m = mx[r];
      m = fmaxf(m, DPPF(m, 0x121));  // row_ror:1
      m = fmaxf(m, DPPF(m, 0x122));  // row_ror:2
      m = fmaxf(m, DPPF(m, 0x124));  // row_ror:4
      m = fmaxf(m, DPPF(m, 0x128));  // row_ror:8
      mx[r] = m;
    }
    float sm[4] = {0.f, 0.f, 0.f, 0.f};
    #pragma unroll
    for (int t = 0; t < 16; t++)
      #pragma unroll
      for (int r = 0; r < 4; r++) {
        float p = __builtin_amdgcn_exp2f(acc[t][r] - mx[r]);
        acc[t][r] = p;
        sm[r] += p;
      }
    #pragma unroll
    for (int r = 0; r < 4; r++) {
      float s = sm[r];
      s += DPPF(s, 0x121);
      s += DPPF(s, 0x122);
      s += DPPF(s, 0x124);
      s += DPPF(s, 0x128);
      sm[r] = 1.f / s;
    }
    // unnormalized P -> LDS (permuted-col layout; normalize in epilogue)
    #pragma unroll
    for (int r = 0; r < 4; r++) {
      half8 h0, h1;
      #pragma unroll
      for (int t = 0; t < 8; t++) h0[t] = (_Float16)acc[t][r];
      #pragma unroll
      for (int t = 0; t < 8; t++) h1[t] = (_Float16)acc[t + 8][r];
      *(half8*)&Ps[w][q4 * 4 + r][mm * 16] = h0;
      *(half8*)&Ps[w][q4 * 4 + r][mm * 16 + 8] = h1;
    }
    // phase 2: out = P @ F (permuted k-order), scale by sm[r]*sv[nt] at write
    f32x4 acc2[4] = {};
    #pragma unroll
    for (int kk = 0; kk < 8; kk++) {
      half8 pa = *(const half8*)&Ps[w][mm][kk * 32 + q4 * 8];
      #pragma unroll
      for (int nt = 0; nt < 4; nt++)
        acc2[nt] = __builtin_amdgcn_mfma_f32_16x16x32_f16(pa, ff[nt][kk], acc2[nt], 0, 0, 0);
    }
    const int rw0 = row_base + tile * 16;
    #pragma unroll
    for (int nt = 0; nt < 4; nt++)
      #pragma unroll
      for (int r = 0; r < 4; r++)
        O[(size_t)(b * SEQ + rw0 + q4 * 4 + r) * DIM + h * HD + nt * 16 + mm] =
            (_Float16)(acc2[nt][r] * (sm[r] * sv[nt]));
    qa0 = qn0;
    qa1 = qn1;
  }
}

extern "C" void kernel_launch(void* const* d_in, const int* in_sizes, int n_in,
                              void* d_out, int out_size, void* d_ws, size_t ws_size,
                              hipStream_t stream) {
  (void)in_sizes; (void)n_in; (void)out_size; (void)ws_size;
  const float* x  = (const float*)d_in[0];
  const float* Wq = (const float*)d_in[1];
  const float* Wk = (const float*)d_in[2];
  const float* Wv = (const float*)d_in[3];
  const float* E  = (const float*)d_in[4];
  const float* F  = (const float*)d_in[5];
  const float* Wo = (const float*)d_in[6];
  const float* bo = (const float*)d_in[7];
  char* ws = (char*)d_ws;
  _Float16* x_h  = (_Float16*)(ws);
  _Float16* O_h  = (_Float16*)(ws);          // aliases x_h (dead after Q GEMM)
  _Float16* Q_h  = (_Float16*)(ws + 33554432);
  _Float16* Wq_h = (_Float16*)(ws + 67108864);
  _Float16* Wo_h = (_Float16*)(ws + 69206016);
  _Float16* E_h  = (_Float16*)(ws + 71303168);
  _Float16* Ft_h = (_Float16*)(ws + 71335936);
  float* xsum    = (float*)(ws + 71368704);
  float* Sk      = (float*)(ws + 71385088);
  float* Sv      = (float*)(ws + 71401472);
  float* out     = (float*)d_out;

  k_cvt<<<8192, 256, 0, stream>>>(x, x_h);
  k_misc<<<88, 256, 0, stream>>>(E, F, E_h, Ft_h, xsum);
  k_cvtw<<<1024, 256, 0, stream>>>(Wq, Wo, Wq_h, Wo_h);
  k_xsum<<<dim3(4, BATCH, 32), 256, 0, stream>>>(x_h, xsum);
  k_sksv<<<2048, 256, 0, stream>>>(xsum, Wk, Wv, Sk, Sv);
  k_gemm<0><<<dim3(128, 8), 256, 0, stream>>>(x_h, Wq_h, (void*)Q_h, Sk);
  k_attn<<<dim3(8, 64), 256, 0, stream>>>(Q_h, E_h, Ft_h, Sv, O_h);
  k_gemm<1><<<dim3(128, 8), 256, 0, stream>>>(O_h, Wo_h, (void*)out, bo);
}